// Round 10
// baseline (547.609 us; speedup 1.0000x reference)
//
#include <hip/hip_runtime.h>

// ---------------------------------------------------------------------------
// RelPositionMultiHeadedAttention (Conformer / Transformer-XL rel-shift)
// B=4, T=2048, C=512, H=8, D=64
//
// R18: register-allocator + pipeline-depth round.
//  - attn (= R17 code): amdgpu_waves_per_eu(4,4) -- R17's allocator targeted
//    8 waves/EU (64-VGPR granule) and spilled the T14 prefetch regs to
//    scratch (WRITE 16.4->21.5MB). Grid gives exactly 4 blocks/CU, so pin
//    the target at 4 waves/EU; prefetch stays in registers.
//  - QKVP: A-prefetch 2 chunks deep (xaA/xaB, unroll-2, static indices) to
//    cover ~900cyc HBM latency on the streamed X; W stays 1-deep (L2-hot).
//    Same chunk order => bit-identical. waves_per_eu(3,3) (170-reg point).
//  - out_gemm/wsplit/launcher = R16/R17-exact.
// ---------------------------------------------------------------------------

#define Bb 4
#define Tt 2048
#define Cc 512
#define Hh 8
#define Dd 64

typedef __bf16 bf16_t;
typedef __bf16 bf16x8 __attribute__((ext_vector_type(8)));
typedef __bf16 bf16x4 __attribute__((ext_vector_type(4)));
typedef float  f32x4  __attribute__((ext_vector_type(4)));

// ---------------------------------------------------------------------------
// Prepass: WT_hi[n][k], WT_lo[n][k] bf16 from W[k][n] f32.
// ---------------------------------------------------------------------------
__global__ __launch_bounds__(256, 4)
void wsplit_kernel(const float* __restrict__ Wq, const float* __restrict__ Wk,
                   const float* __restrict__ Wv, const float* __restrict__ Wp,
                   const float* __restrict__ Wo,
                   bf16_t* __restrict__ WT4, bf16_t* __restrict__ WoT, int mode)
{
    const int w = (mode < 0) ? (int)blockIdx.y : 4;
    const float* W = (w == 0) ? Wq : (w == 1) ? Wk : (w == 2) ? Wv : (w == 3) ? Wp : Wo;
    bf16_t* dh = (w == 4) ? WoT : WT4 + (size_t)w * 2 * 262144;
    bf16_t* dl = dh + 262144;

    const int tile = blockIdx.x;           // 64 tiles of 64x64
    const int k0 = (tile >> 3) * 64;
    const int n0 = (tile & 7) * 64;
    const int tid = threadIdx.x;

    __shared__ bf16_t th[64][66];
    __shared__ bf16_t tl[64][66];

#pragma unroll
    for (int rep = 0; rep < 4; rep++) {
        int id = rep * 256 + tid;          // 1024 ids: 64 k-rows x 16 f32x4 segs
        int kk = id >> 4, ns = id & 15;
        f32x4 v = *(const f32x4*)&W[(size_t)(k0 + kk) * 512 + n0 + ns * 4];
#pragma unroll
        for (int e = 0; e < 4; e++) {
            bf16_t h = (bf16_t)v[e];
            th[kk][ns * 4 + e] = h;
            tl[kk][ns * 4 + e] = (bf16_t)(v[e] - (float)h);
        }
    }
    __syncthreads();
#pragma unroll
    for (int rep = 0; rep < 2; rep++) {
        int id = rep * 256 + tid;          // 512 ids: 64 n-rows x 8 k-segs
        int nn = id >> 3, ks = id & 7;
        bf16x8 hv, lv;
#pragma unroll
        for (int j = 0; j < 8; j++) { hv[j] = th[ks * 8 + j][nn]; lv[j] = tl[ks * 8 + j][nn]; }
        *(bf16x8*)&dh[(size_t)(n0 + nn) * 512 + k0 + ks * 8] = hv;
        *(bf16x8*)&dl[(size_t)(n0 + nn) * 512 + k0 + ks * 8] = lv;
    }
}

// ---------------------------------------------------------------------------
// QKVP split-bf16 GEMM, BK=32, A-prefetch depth 2 (xaA/xaB, unroll-2).
// z = blockIdx.z: 0=Q(->QU,QV) 1=K 2=V(->VT) 3=P.
// ---------------------------------------------------------------------------
__global__ __launch_bounds__(256) __attribute__((amdgpu_waves_per_eu(3, 3)))
void split_gemm_kernel(const float* __restrict__ Xq, const float* __restrict__ Xk,
                       const float* __restrict__ Xv, const float* __restrict__ Xp,
                       const bf16_t* __restrict__ WT4,
                       const float* __restrict__ bq, const float* __restrict__ bk,
                       const float* __restrict__ bv,
                       const float* __restrict__ bias_u, const float* __restrict__ bias_v,
                       bf16_t* __restrict__ QU, bf16_t* __restrict__ QV,
                       bf16_t* __restrict__ K16, bf16_t* __restrict__ VT16,
                       bf16_t* __restrict__ P16)
{
    const int z = blockIdx.z;
    const float* X    = (z == 0) ? Xq : (z == 1) ? Xk : (z == 2) ? Xv : Xp;
    const bf16_t* Wh  = WT4 + (size_t)z * 2 * 262144;
    const bf16_t* Wl  = Wh + 262144;
    const float* bias = (z == 0) ? bq : (z == 1) ? bk : (z == 2) ? bv : nullptr;

    const int bx = blockIdx.x;
    const int g  = bx >> 3, x8 = bx & 7;
    const int mtile = (g >> 2) * 8 + x8;   // 0..63
    const int ntile = g & 3;               // 0..3
    const int r0 = mtile * 128;
    const int c0 = ntile * 128;

    const int tid  = threadIdx.x;
    const int wave = tid >> 6;
    const int lane = tid & 63;
    const int quad = lane >> 4;
    const int l16  = lane & 15;
    const int rb = (wave >> 1) * 64;
    const int cb = (wave & 1) * 64;

    __shared__ __align__(16) bf16_t Ah[128][40];
    __shared__ __align__(16) bf16_t Al[128][40];
    __shared__ __align__(16) bf16_t Bh[128][40];
    __shared__ __align__(16) bf16_t Bl[128][40];

    f32x4 acc[4][4];
#pragma unroll
    for (int mt = 0; mt < 4; mt++)
#pragma unroll
        for (int nt = 0; nt < 4; nt++)
#pragma unroll
            for (int r = 0; r < 4; r++) acc[mt][nt][r] = 0.f;

    // staging id decomposition
    const int am = tid >> 3, ac = tid & 7;     // A: row tid>>3 (+32 per rep), f32x4 seg
    const int bn = tid >> 2, bs = tid & 3;     // B: row tid>>2 (+64 per rep), bf16x8 seg

    // staged-tile registers: A 2-deep, W 1-deep
    f32x4  xaA[4], xaB[4];
    bf16x8 wbh[2], wbl[2];

#define LOADA(dst, kk)                                                          \
    {                                                                           \
        _Pragma("unroll")                                                       \
        for (int rep = 0; rep < 4; rep++)                                       \
            dst[rep] = *(const f32x4*)&X[(size_t)(r0 + am + rep * 32) * 512 + (kk) + ac * 4]; \
    }
#define LOADW(kk)                                                               \
    {                                                                           \
        _Pragma("unroll")                                                       \
        for (int rep = 0; rep < 2; rep++) {                                     \
            wbh[rep] = *(const bf16x8*)&Wh[(size_t)(c0 + bn + rep * 64) * 512 + (kk) + bs * 8]; \
            wbl[rep] = *(const bf16x8*)&Wl[(size_t)(c0 + bn + rep * 64) * 512 + (kk) + bs * 8]; \
        }                                                                       \
    }
#define WRITE(src)                                                              \
    {                                                                           \
        _Pragma("unroll")                                                       \
        for (int rep = 0; rep < 4; rep++) {                                     \
            f32x4 v = src[rep];                                                 \
            bf16x4 hh, ll;                                                      \
            _Pragma("unroll")                                                   \
            for (int e = 0; e < 4; e++) {                                       \
                bf16_t hv = (bf16_t)v[e];                                       \
                hh[e] = hv;                                                     \
                ll[e] = (bf16_t)(v[e] - (float)hv);                             \
            }                                                                   \
            *(bf16x4*)&Ah[am + rep * 32][ac * 4] = hh;                          \
            *(bf16x4*)&Al[am + rep * 32][ac * 4] = ll;                          \
        }                                                                       \
        _Pragma("unroll")                                                       \
        for (int rep = 0; rep < 2; rep++) {                                     \
            *(bf16x8*)&Bh[bn + rep * 64][bs * 8] = wbh[rep];                    \
            *(bf16x8*)&Bl[bn + rep * 64][bs * 8] = wbl[rep];                    \
        }                                                                       \
    }
#define COMPUTE()                                                               \
    {                                                                           \
        bf16x8 bh[4], bl[4], ah[4], al[4];                                      \
        _Pragma("unroll")                                                       \
        for (int nt = 0; nt < 4; nt++) {                                        \
            bh[nt] = *(const bf16x8*)&Bh[cb + nt * 16 + l16][quad * 8];         \
            bl[nt] = *(const bf16x8*)&Bl[cb + nt * 16 + l16][quad * 8];         \
        }                                                                       \
        _Pragma("unroll")                                                       \
        for (int mt = 0; mt < 4; mt++) {                                        \
            ah[mt] = *(const bf16x8*)&Ah[rb + mt * 16 + l16][quad * 8];         \
            al[mt] = *(const bf16x8*)&Al[rb + mt * 16 + l16][quad * 8];         \
        }                                                                       \
        _Pragma("unroll")                                                       \
        for (int mt = 0; mt < 4; mt++) {                                        \
            _Pragma("unroll")                                                   \
            for (int nt = 0; nt < 4; nt++) {                                    \
                acc[mt][nt] = __builtin_amdgcn_mfma_f32_16x16x32_bf16(ah[mt], bh[nt], acc[mt][nt], 0, 0, 0); \
                acc[mt][nt] = __builtin_amdgcn_mfma_f32_16x16x32_bf16(ah[mt], bl[nt], acc[mt][nt], 0, 0, 0); \
                acc[mt][nt] = __builtin_amdgcn_mfma_f32_16x16x32_bf16(al[mt], bh[nt], acc[mt][nt], 0, 0, 0); \
            }                                                                   \
        }                                                                       \
    }

    // prologue: A chunks 0,1; W chunk 0
    LOADA(xaA, 0);
    LOADA(xaB, 32);
    LOADW(0);

#pragma unroll 1
    for (int it2 = 0; it2 < 8; ++it2) {
        const int c = it2 * 2;             // even chunk index
        // ---- even chunk c: A in xaA, W current ----
        WRITE(xaA);
        __syncthreads();
        if (c + 2 < 16) LOADA(xaA, (c + 2) * 32);
        LOADW((c + 1) * 32);
        COMPUTE();
        __syncthreads();
        // ---- odd chunk c+1: A in xaB, W current ----
        WRITE(xaB);
        __syncthreads();
        if (c + 3 < 16) LOADA(xaB, (c + 3) * 32);
        if (c + 2 < 16) LOADW((c + 2) * 32);
        COMPUTE();
        __syncthreads();
    }
#undef LOADA
#undef LOADW
#undef WRITE
#undef COMPUTE

#pragma unroll
    for (int mt = 0; mt < 4; mt++) {
#pragma unroll
        for (int r = 0; r < 4; r++) {
            int row = r0 + rb + mt * 16 + quad * 4 + r;
#pragma unroll
            for (int nt = 0; nt < 4; nt++) {
                int col = c0 + cb + nt * 16 + l16;
                float y = acc[mt][nt][r] + (bias ? bias[col] : 0.f);
                int b = row >> 11, t = row & 2047;
                int h = col >> 6,  d = col & 63;
                if (z == 0) {
                    size_t idx = (((size_t)(b * Hh + h)) * Tt + t) * Dd + d;
                    QU[idx] = (bf16_t)(y + bias_u[col]);
                    QV[idx] = (bf16_t)(y + bias_v[col]);
                } else if (z == 1) {
                    size_t idx = (((size_t)(b * Hh + h)) * Tt + t) * Dd + d;
                    K16[idx] = (bf16_t)y;
                } else if (z == 2) {
                    // transposed: VT[bh][d][t]
                    size_t idx = (((size_t)(b * Hh + h)) * Dd + d) * Tt + t;
                    VT16[idx] = (bf16_t)y;
                } else {
                    size_t idx = (((size_t)(b * Hh + h)) * Tt + t) * Dd + d;
                    P16[idx] = (bf16_t)y;
                }
            }
        }
    }
}

// ---------------------------------------------------------------------------
// Out-projection GEMM (R16-exact): OUT = CTX @ Wo + bo. 64x128 tiles.
// ---------------------------------------------------------------------------
__global__ __launch_bounds__(256, 2)
void out_gemm_kernel(const float* __restrict__ Xc, const bf16_t* __restrict__ WoT,
                     const float* __restrict__ bo, float* __restrict__ OUT)
{
    const bf16_t* Wh = WoT;
    const bf16_t* Wl = WoT + 262144;

    const int bx = blockIdx.x;             // 512 blocks: 128 mtiles x 4 ntiles
    const int r0 = (bx >> 2) * 64;
    const int c0 = (bx & 3) * 128;

    const int tid  = threadIdx.x;
    const int wave = tid >> 6;
    const int lane = tid & 63;
    const int quad = lane >> 4;
    const int l16  = lane & 15;
    const int rb = (wave >> 1) * 32;
    const int cb = (wave & 1) * 64;

    __shared__ __align__(16) bf16_t Ah[64][72];
    __shared__ __align__(16) bf16_t Al[64][72];
    __shared__ __align__(16) bf16_t Bh[128][72];
    __shared__ __align__(16) bf16_t Bl[128][72];

    f32x4 acc[2][4];
#pragma unroll
    for (int mt = 0; mt < 2; mt++)
#pragma unroll
        for (int nt = 0; nt < 4; nt++)
#pragma unroll
            for (int r = 0; r < 4; r++) acc[mt][nt][r] = 0.f;

    f32x4  xa[4];
    bf16x8 wbh[4], wbl[4];

    // prologue: K-step 0
#pragma unroll
    for (int rep = 0; rep < 4; rep++) {
        int id = rep * 256 + tid;          // 1024 ids: 64 rows x 16 f32x4 segs
        int m = id >> 4, c = id & 15;
        xa[rep] = *(const f32x4*)&Xc[(size_t)(r0 + m) * 512 + c * 4];
    }
#pragma unroll
    for (int rep = 0; rep < 4; rep++) {
        int id = rep * 256 + tid;          // 1024 ids: 128 rows x 8 k-segs
        int n = id >> 3, seg = id & 7;
        wbh[rep] = *(const bf16x8*)&Wh[(size_t)(c0 + n) * 512 + seg * 8];
        wbl[rep] = *(const bf16x8*)&Wl[(size_t)(c0 + n) * 512 + seg * 8];
    }

    for (int it = 0; it < 8; ++it) {
#pragma unroll
        for (int rep = 0; rep < 4; rep++) {
            int id = rep * 256 + tid;
            int m = id >> 4, c = id & 15;
            f32x4 v = xa[rep];
            bf16x4 hh, ll;
#pragma unroll
            for (int e = 0; e < 4; e++) {
                bf16_t hv = (bf16_t)v[e];
                hh[e] = hv;
                ll[e] = (bf16_t)(v[e] - (float)hv);
            }
            *(bf16x4*)&Ah[m][c * 4] = hh;
            *(bf16x4*)&Al[m][c * 4] = ll;
        }
#pragma unroll
        for (int rep = 0; rep < 4; rep++) {
            int id = rep * 256 + tid;
            int n = id >> 3, seg = id & 7;
            *(bf16x8*)&Bh[n][seg * 8] = wbh[rep];
            *(bf16x8*)&Bl[n][seg * 8] = wbl[rep];
        }
        __syncthreads();

        if (it < 7) {
            const int k0n = (it + 1) * 64;
#pragma unroll
            for (int rep = 0; rep < 4; rep++) {
                int id = rep * 256 + tid;
                int m = id >> 4, c = id & 15;
                xa[rep] = *(const f32x4*)&Xc[(size_t)(r0 + m) * 512 + k0n + c * 4];
            }
#pragma unroll
            for (int rep = 0; rep < 4; rep++) {
                int id = rep * 256 + tid;
                int n = id >> 3, seg = id & 7;
                wbh[rep] = *(const bf16x8*)&Wh[(size_t)(c0 + n) * 512 + k0n + seg * 8];
                wbl[rep] = *(const bf16x8*)&Wl[(size_t)(c0 + n) * 512 + k0n + seg * 8];
            }
        }

#pragma unroll
        for (int kc = 0; kc < 2; kc++) {
            bf16x8 bh[4], bl[4], ah[2], al[2];
#pragma unroll
            for (int nt = 0; nt < 4; nt++) {
                bh[nt] = *(const bf16x8*)&Bh[cb + nt * 16 + l16][kc * 32 + quad * 8];
                bl[nt] = *(const bf16x8*)&Bl[cb + nt * 16 + l16][kc * 32 + quad * 8];
            }
#pragma unroll
            for (int mt = 0; mt < 2; mt++) {
                ah[mt] = *(const bf16x8*)&Ah[rb + mt * 16 + l16][kc * 32 + quad * 8];
                al[mt] = *(const bf16x8*)&Al[rb + mt * 16 + l16][kc * 32 + quad * 8];
            }
#pragma unroll
            for (int mt = 0; mt < 2; mt++) {
#pragma unroll
                for (int nt = 0; nt < 4; nt++) {
                    acc[mt][nt] = __builtin_amdgcn_mfma_f32_16x16x32_bf16(ah[mt], bh[nt], acc[mt][nt], 0, 0, 0);
                    acc[mt][nt] = __builtin_amdgcn_mfma_f32_16x16x32_bf16(ah[mt], bl[nt], acc[mt][nt], 0, 0, 0);
                    acc[mt][nt] = __builtin_amdgcn_mfma_f32_16x16x32_bf16(al[mt], bh[nt], acc[mt][nt], 0, 0, 0);
                }
            }
        }
        __syncthreads();
    }

#pragma unroll
    for (int mt = 0; mt < 2; mt++) {
#pragma unroll
        for (int r = 0; r < 4; r++) {
            int row = r0 + rb + mt * 16 + quad * 4 + r;
#pragma unroll
            for (int nt = 0; nt < 4; nt++) {
                int col = c0 + cb + nt * 16 + l16;
                OUT[(size_t)row * 512 + col] = acc[mt][nt][r] + bo[col];
            }
        }
    }
}

// ---------------------------------------------------------------------------
// Kernel 2: attention with T14 async-stage split (R17 code; allocator pinned
// at 4 waves/EU so prefetch regs stay in VGPRs). grid = (bh=32, itile=32).
// LDS map (bytes), total 38912 (R12 layout, unchanged).
// ---------------------------------------------------------------------------
struct Band { int d_hi, w1, prow1, w2, e_lo, c2_0, nct1, nct2; };

__device__ __forceinline__ Band mkband(int i0, int j0)
{
    Band b;
    int d_lo = i0 - (j0 + 63);
    b.d_hi = i0 + 63 - j0;
    b.w1 = 0; b.prow1 = 0;
    if (b.d_hi >= 0) {
        int b1 = d_lo > 0 ? d_lo : 0;
        b.w1 = b.d_hi - b1 + 1;
        b.prow1 = (Tt - 1) - b.d_hi;
    }
    int dmax2 = b.d_hi < -2 ? b.d_hi : -2;
    b.w2 = 0; b.e_lo = 0;
    if (d_lo <= dmax2) {
        b.e_lo = -dmax2 - 2;
        int e_hi = -d_lo - 2;
        b.w2 = e_hi - b.e_lo + 1;
    }
    b.c2_0 = b.d_hi + 2 + b.e_lo;
    b.nct1 = (b.w1 + 15) >> 4;
    b.nct2 = (b.w2 + 15) >> 4;
    return b;
}

__global__ __launch_bounds__(256) __attribute__((amdgpu_waves_per_eu(4, 4)))
void attn_kernel(const bf16_t* __restrict__ QU, const bf16_t* __restrict__ QV,
                 const bf16_t* __restrict__ K16, const bf16_t* __restrict__ VT16,
                 const bf16_t* __restrict__ P16, float* __restrict__ CTX)
{
    const int bh = blockIdx.x;                 // XCD locality: linear%8 = bh%8
    const int i0 = blockIdx.y * 64;
    const int b = bh >> 3, h = bh & 7;
    const int tid = threadIdx.x;
    const int wave = tid >> 6;
    const int lane = tid & 63;
    const int quad = lane >> 4;
    const int l16 = lane & 15;

    const bf16_t* qu_g = QU + (size_t)bh * Tt * Dd;
    const bf16_t* qv_g = QV + (size_t)bh * Tt * Dd;
    const bf16_t* k_g  = K16 + (size_t)bh * Tt * Dd;
    const bf16_t* vt_g = VT16 + (size_t)bh * Dd * Tt;   // [d][t]
    const bf16_t* p_g  = P16 + (size_t)bh * Tt * Dd;

    __shared__ __align__(16) char smem[38912];
    bf16_t (*pA)[72]  = (bf16_t (*)[72])(smem);           // 128 rows (P band)
    bf16_t (*k_s)[72] = (bf16_t (*)[72])(smem + 18432);   // 64 rows
    bf16_t (*msw)[88] = (bf16_t (*)[88])(smem + 27648);   // 64 rows, strip-local

    const int off_w = 48 - wave * 16;          // strip-local = absolute - off_w
    const int cmin = 48 - wave * 16;           // absolute strip window
    const int cmax = 126 - wave * 16;

    // staging id decomposition (same for K and P paths)
    const int srow = tid >> 3;                 // 0..31
    const int sseg = tid & 7;                  // 0..7

    // A-operand fragments, direct global loads: A[m=l16][k=quad*8+e]
    const int qrow = i0 + wave * 16 + l16;
    const int qrow2 = (qrow + 1 > Tt - 1) ? (Tt - 1) : (qrow + 1);  // clamped row never gathered
    bf16x8 aq[2], av1[2], av2[2];
#pragma unroll
    for (int kc = 0; kc < 2; kc++) {
        aq[kc]  = *(const bf16x8*)(qu_g + (size_t)qrow  * Dd + kc * 32 + quad * 8);
        av1[kc] = *(const bf16x8*)(qv_g + (size_t)qrow  * Dd + kc * 32 + quad * 8);
        av2[kc] = *(const bf16x8*)(qv_g + (size_t)qrow2 * Dd + kc * 32 + quad * 8);
    }

    float lsum[4];
    f32x4 accO[4];
#pragma unroll
    for (int r = 0; r < 4; r++) lsum[r] = 0.f;
#pragma unroll
    for (int dt = 0; dt < 4; dt++)
#pragma unroll
        for (int r = 0; r < 4; r++) accO[dt][r] = 0.f;

    // --- T14 prefetch registers (named scalars; no arrays -> no scratch) ---
    f32x4 kr0, kr1, pr0, pr1, pr2, pr3;
    Band bp = mkband(i0, 0);
    {
        kr0 = *(const f32x4*)(k_g + (size_t)(0 + srow) * Dd + sseg * 8);
        kr1 = *(const f32x4*)(k_g + (size_t)(0 + srow + 32) * Dd + sseg * 8);
        int r0_ = srow,      s0 = (r0_ < bp.w1) ? bp.prow1 + r0_ : bp.e_lo + r0_ - bp.w1;
        int r1_ = srow + 32, s1 = (r1_ < bp.w1) ? bp.prow1 + r1_ : bp.e_lo + r1_ - bp.w1;
        int r2_ = srow + 64, s2 = (r2_ < bp.w1) ? bp.prow1 + r2_ : bp.e_lo + r2_ - bp.w1;
        int r3_ = srow + 96, s3 = (r3_ < bp.w1) ? bp.prow1 + r3_ : bp.e_lo + r3_ - bp.w1;
        if (s0 > Tt - 1) s0 = Tt - 1;
        if (s1 > Tt - 1) s1 = Tt - 1;
        if (s2 > Tt - 1) s2 = Tt - 1;
        if (s3 > Tt - 1) s3 = Tt - 1;
        pr0 = *(const f32x4*)(p_g + (size_t)s0 * Dd + sseg * 8);
        pr1 = *(const f32x4*)(p_g + (size_t)s1 * Dd + sseg * 8);
        pr2 = *(const f32x4*)(p_g + (size_t)s2 * Dd + sseg * 8);
        pr3 = *(const f32x4*)(p_g + (size_t)s3 * Dd + sseg * 8);
    }

    for (int j0 = 0; j0 < Tt; j0 += 64) {
        const Band bc = bp;

        // write prefetched regs to LDS (same addresses/guards as staged path)
        *(f32x4*)&k_s[srow][sseg * 8]      = kr0;
        *(f32x4*)&k_s[srow + 32][sseg * 8] = kr1;
        {
            int wtot = bc.w1 + bc.w2;
            if (srow < wtot)      *(f32x4*)&pA[srow][sseg * 8]      = pr0;
            if (srow + 32 < wtot) *(f32x4*)&pA[srow + 32][sseg * 8] = pr1;
            if (srow + 64 < wtot) *(f32x4*)&pA[srow + 64][sseg * 8] = pr2;
            if (srow + 96 < wtot) *(f32x4*)&pA[srow + 96][sseg * 8] = pr3;
        }
        __syncthreads();

        // issue next tile's K/P loads now; they fly under the compute below
        if (j0 + 64 < Tt) {
            bp = mkband(i0, j0 + 64);
            kr0 = *(const f32x4*)(k_g + (size_t)(j0 + 64 + srow) * Dd + sseg * 8);
            kr1 = *(const f32x4*)(k_g + (size_t)(j0 + 64 + srow + 32) * Dd + sseg * 8);
            int r0_ = srow,      s0 = (r0_ < bp.w1) ? bp.prow1 + r0_ : bp.e_lo + r0_ - bp.w1;
            int r1_ = srow + 32, s1 = (r1_ < bp.w1) ? bp.prow1 + r1_ : bp.e_lo + r1_ - bp.w1;
            int r2_ = srow + 64, s2 = (r2_ < bp.w1) ? bp.prow1 + r2_ : bp.e_lo + r2_ - bp.w1;
            int r3_ = srow + 96, s3 = (r3_ < bp.w1) ? bp.prow1 + r3_ : bp.e_lo + r3_ - bp.w1;
            if (s0 > Tt - 1) s0 = Tt - 1;
            if (s1 > Tt - 1) s1 = Tt - 1;
            if (s2 > Tt - 1) s2 = Tt - 1;
            if (s3 > Tt - 1) s3 = Tt - 1;
            pr0 = *(const f32x4*)(p_g + (size_t)s0 * Dd + sseg * 8);
            pr1 = *(const f32x4*)(p_g + (size_t)s1 * Dd + sseg * 8);
            pr2 = *(const f32x4*)(p_g + (size_t)s2 * Dd + sseg * 8);
            pr3 = *(const f32x4*)(p_g + (size_t)s3 * Dd + sseg * 8);
        }

        // content scores
        f32x4 accS[4];
#pragma unroll
        for (int nt = 0; nt < 4; nt++) {
            f32x4 acc = {0.f, 0.f, 0.f, 0.f};
#pragma unroll
            for (int kc = 0; kc < 2; kc++) {
                bf16x8 bk8 = *(const bf16x8*)&k_s[nt * 16 + l16][kc * 32 + quad * 8];
                acc = __builtin_amdgcn_mfma_f32_16x16x32_bf16(aq[kc], bk8, acc, 0, 0, 0);
            }
            accS[nt] = acc;
        }

        // banded pos matmul -> strip-local skewed store (wave-private)
        for (int ct = 0; ct < bc.nct1 + bc.nct2; ct++) {
            bool b2 = ct >= bc.nct1;
            int rb_ = b2 ? (bc.w1 + (ct - bc.nct1) * 16) : (ct * 16);
            int cb_ = b2 ? (bc.c2_0 + (ct - bc.nct1) * 16) : (ct * 16);
            if (cb_ > cmax || cb_ + 15 < cmin) continue;
            f32x4 acc = {0.f, 0.f, 0.f, 0.f};
#pragma unroll
            for (int kc = 0; kc < 2; kc++) {
                bf16x8 bp8 = *(const bf16x8*)&pA[rb_ + l16][kc * 32 + quad * 8];
                acc = b2 ? __builtin_amdgcn_mfma_f32_16x16x32_bf16(av2[kc], bp8, acc, 0, 0, 0)
                         : __builtin_amdgcn_mfma_f32_16x16x32_bf16(av1[kc], bp8, acc, 0, 0, 0);
            }
            int colp = cb_ + l16 - off_w;          // strip-local
            if ((unsigned)colp < 80u) {
#pragma unroll
                for (int r = 0; r < 4; r++)
                    msw[wave * 16 + quad * 4 + r][colp] = (bf16_t)acc[r];
            }
        }
        // zero column for dd == -1 (strip-local)
        {
            int zcl = bc.d_hi + 1 - off_w;
            if ((unsigned)zcl < 80u && quad == 0)
                msw[wave * 16 + l16][zcl] = (bf16_t)0.f;
        }

        // gather all 16 (no aliasing stores in between), then write weights
        float wv[4][4];
#pragma unroll
        for (int nt = 0; nt < 4; nt++) {
#pragma unroll
            for (int r = 0; r < 4; r++) {
                float pos = (float)msw[wave * 16 + quad * 4 + r]
                                    [nt * 16 + l16 + 15 - (quad * 4 + r)];
                float x = accS[nt][r] + pos;
                float a = fminf(fmaf(x, 0.18033688f, -17.3123405f), 120.0f);
                float w = exp2f(a);
                lsum[r] += w;
                wv[nt][r] = w;
            }
        }
#pragma unroll
        for (int nt = 0; nt < 4; nt++)
#pragma unroll
            for (int r = 0; r < 4; r++)
                msw[wave * 16 + quad * 4 + r][nt * 16 + l16] = (bf16_t)wv[nt][r];

        // O += W @ V : A from own msw strip, B direct from VT ([d][t])
#pragma unroll
        for (int kc = 0; kc < 2; kc++) {
            bf16x8 aw = *(const bf16x8*)&msw[wave * 16 + l16][kc * 32 + quad * 8];
#pragma unroll
            for (int dt = 0; dt < 4; dt++) {
                bf16x8 bv8 = *(const bf16x8*)(vt_g + (size_t)(dt * 16 + l16) * Tt + j0 + kc * 32 + quad * 8);
                accO[dt] = __builtin_amdgcn_mfma_f32_16x16x32_bf16(aw, bv8, accO[dt], 0, 0, 0);
            }
        }
        __syncthreads();  // protect k_s/pA before next write phase
    }

#pragma unroll
    for (int r = 0; r < 4; r++) {
#pragma unroll
        for (int off = 1; off < 16; off <<= 1) lsum[r] += __shfl_xor(lsum[r], off, 64);
    }

#pragma unroll
    for (int r = 0; r < 4; r++) {
        int il = wave * 16 + quad * 4 + r;
        int ig = i0 + il;
        float inv = 1.0f / lsum[r];
#pragma unroll
        for (int dt = 0; dt < 4; dt++) {
            CTX[((size_t)(b * Tt + ig)) * Cc + h * Dd + dt * 16 + l16] = accO[dt][r] * inv;
        }
    }
}

// ---------------------------------------------------------------------------
extern "C" void kernel_launch(void* const* d_in, const int* in_sizes, int n_in,
                              void* d_out, int out_size, void* d_ws, size_t ws_size,
                              hipStream_t stream)
{
    const float* query = (const float*)d_in[0];
    const float* key   = (const float*)d_in[1];
    const float* value = (const float*)d_in[2];
    const float* pemb  = (const float*)d_in[3];
    const float* Wq    = (const float*)d_in[4];
    const float* bq    = (const float*)d_in[5];
    const float* Wk    = (const float*)d_in[6];
    const float* bk    = (const float*)d_in[7];
    const float* Wv    = (const float*)d_in[8];
    const float* bv    = (const float*)d_in[9];
    const float* Wpos  = (const float*)d_in[10];
    const float* pbu   = (const float*)d_in[11];
    const float* pbv   = (const float*)d_in[12];
    const float* Wo    = (const float*)d_in[13];
    const float* bo    = (const float*)d_in[14];

    const size_t NE = (size_t)Bb * Hh * Tt * Dd;  // 4,194,304 per tensor
    bf16_t* QU   = (bf16_t*)d_ws;
    bf16_t* QV   = QU + NE;
    bf16_t* K16  = QV + NE;
    bf16_t* VT16 = K16 + NE;
    bf16_t* P16  = VT16 + NE;
    float*  CTX  = (float*)(P16 + NE);            // ws >= 56 MB (unchanged)

    // W^T hi/lo planes overlaid on dead regions (no extra workspace):
    //  - WT4 (Wq,Wk,Wv,Wpos; 4 MB) in CTX region: dead until attn writes CTX.
    //  - WoT (1 MB) in QU region: written AFTER attn (QU dead by then).
    bf16_t* WT4 = (bf16_t*)CTX;
    bf16_t* WoT = (bf16_t*)QU;

    // prepass A: Wq/Wk/Wv/Wpos -> transposed hi/lo bf16 planes
    wsplit_kernel<<<dim3(64, 4), 256, 0, stream>>>(Wq, Wk, Wv, Wpos, Wo, WT4, WoT, -1);

    // QKVP projections (z = blockIdx.z)
    split_gemm_kernel<<<dim3(256, 1, 4), 256, 0, stream>>>(
        query, key, value, pemb, WT4,
        bq, bk, bv, pbu, pbv, QU, QV, K16, VT16, P16);

    attn_kernel<<<dim3(32, 32), 256, 0, stream>>>(QU, QV, K16, VT16, P16, CTX);

    // prepass B: Wo -> WoT (QU region now dead)
    wsplit_kernel<<<dim3(64, 1), 256, 0, stream>>>(Wq, Wk, Wv, Wpos, Wo, WT4, WoT, 4);

    // output projection: 64x128 tiles, 512 blocks
    out_gemm_kernel<<<dim3(512), 256, 0, stream>>>(CTX, WoT, bo, (float*)d_out);
}

// Round 11
// 411.299 us; speedup vs baseline: 1.3314x; 1.3314x over previous
//
#include <hip/hip_runtime.h>

// ---------------------------------------------------------------------------
// RelPositionMultiHeadedAttention (Conformer / Transformer-XL rel-shift)
// B=4, T=2048, C=512, H=8, D=64
//
// R19: revert to R17 (verified 410us) after R18's allocator-attribute spill
// storm (split_gemm VGPR 84, 430MB scratch traffic). Single lever:
// out_gemm BK 64->32 (same proven transform as R16's QKVP change):
// LDS 30720 B -> 4 blocks/CU @ lb(256,4); same K-chunk order => bit-identical.
// ---------------------------------------------------------------------------

#define Bb 4
#define Tt 2048
#define Cc 512
#define Hh 8
#define Dd 64

typedef __bf16 bf16_t;
typedef __bf16 bf16x8 __attribute__((ext_vector_type(8)));
typedef __bf16 bf16x4 __attribute__((ext_vector_type(4)));
typedef float  f32x4  __attribute__((ext_vector_type(4)));

// ---------------------------------------------------------------------------
// Prepass: WT_hi[n][k], WT_lo[n][k] bf16 from W[k][n] f32.
// ---------------------------------------------------------------------------
__global__ __launch_bounds__(256, 4)
void wsplit_kernel(const float* __restrict__ Wq, const float* __restrict__ Wk,
                   const float* __restrict__ Wv, const float* __restrict__ Wp,
                   const float* __restrict__ Wo,
                   bf16_t* __restrict__ WT4, bf16_t* __restrict__ WoT, int mode)
{
    const int w = (mode < 0) ? (int)blockIdx.y : 4;
    const float* W = (w == 0) ? Wq : (w == 1) ? Wk : (w == 2) ? Wv : (w == 3) ? Wp : Wo;
    bf16_t* dh = (w == 4) ? WoT : WT4 + (size_t)w * 2 * 262144;
    bf16_t* dl = dh + 262144;

    const int tile = blockIdx.x;           // 64 tiles of 64x64
    const int k0 = (tile >> 3) * 64;
    const int n0 = (tile & 7) * 64;
    const int tid = threadIdx.x;

    __shared__ bf16_t th[64][66];
    __shared__ bf16_t tl[64][66];

#pragma unroll
    for (int rep = 0; rep < 4; rep++) {
        int id = rep * 256 + tid;          // 1024 ids: 64 k-rows x 16 f32x4 segs
        int kk = id >> 4, ns = id & 15;
        f32x4 v = *(const f32x4*)&W[(size_t)(k0 + kk) * 512 + n0 + ns * 4];
#pragma unroll
        for (int e = 0; e < 4; e++) {
            bf16_t h = (bf16_t)v[e];
            th[kk][ns * 4 + e] = h;
            tl[kk][ns * 4 + e] = (bf16_t)(v[e] - (float)h);
        }
    }
    __syncthreads();
#pragma unroll
    for (int rep = 0; rep < 2; rep++) {
        int id = rep * 256 + tid;          // 512 ids: 64 n-rows x 8 k-segs
        int nn = id >> 3, ks = id & 7;
        bf16x8 hv, lv;
#pragma unroll
        for (int j = 0; j < 8; j++) { hv[j] = th[ks * 8 + j][nn]; lv[j] = tl[ks * 8 + j][nn]; }
        *(bf16x8*)&dh[(size_t)(n0 + nn) * 512 + k0 + ks * 8] = hv;
        *(bf16x8*)&dl[(size_t)(n0 + nn) * 512 + k0 + ks * 8] = lv;
    }
}

// ---------------------------------------------------------------------------
// QKVP split-bf16 GEMM, BK=32 (R16/R17-exact).
// z = blockIdx.z: 0=Q(->QU,QV) 1=K 2=V(->VT) 3=P.
// ---------------------------------------------------------------------------
__global__ __launch_bounds__(256, 3)
void split_gemm_kernel(const float* __restrict__ Xq, const float* __restrict__ Xk,
                       const float* __restrict__ Xv, const float* __restrict__ Xp,
                       const bf16_t* __restrict__ WT4,
                       const float* __restrict__ bq, const float* __restrict__ bk,
                       const float* __restrict__ bv,
                       const float* __restrict__ bias_u, const float* __restrict__ bias_v,
                       bf16_t* __restrict__ QU, bf16_t* __restrict__ QV,
                       bf16_t* __restrict__ K16, bf16_t* __restrict__ VT16,
                       bf16_t* __restrict__ P16)
{
    const int z = blockIdx.z;
    const float* X    = (z == 0) ? Xq : (z == 1) ? Xk : (z == 2) ? Xv : Xp;
    const bf16_t* Wh  = WT4 + (size_t)z * 2 * 262144;
    const bf16_t* Wl  = Wh + 262144;
    const float* bias = (z == 0) ? bq : (z == 1) ? bk : (z == 2) ? bv : nullptr;

    const int bx = blockIdx.x;
    const int g  = bx >> 3, x8 = bx & 7;
    const int mtile = (g >> 2) * 8 + x8;   // 0..63
    const int ntile = g & 3;               // 0..3
    const int r0 = mtile * 128;
    const int c0 = ntile * 128;

    const int tid  = threadIdx.x;
    const int wave = tid >> 6;
    const int lane = tid & 63;
    const int quad = lane >> 4;
    const int l16  = lane & 15;
    const int rb = (wave >> 1) * 64;
    const int cb = (wave & 1) * 64;

    __shared__ __align__(16) bf16_t Ah[128][40];
    __shared__ __align__(16) bf16_t Al[128][40];
    __shared__ __align__(16) bf16_t Bh[128][40];
    __shared__ __align__(16) bf16_t Bl[128][40];

    f32x4 acc[4][4];
#pragma unroll
    for (int mt = 0; mt < 4; mt++)
#pragma unroll
        for (int nt = 0; nt < 4; nt++)
#pragma unroll
            for (int r = 0; r < 4; r++) acc[mt][nt][r] = 0.f;

    // staged-tile registers (BK=32)
    f32x4  xa[4];
    bf16x8 wbh[2], wbl[2];

    // prologue: K-chunk 0
#pragma unroll
    for (int rep = 0; rep < 4; rep++) {
        int id = rep * 256 + tid;          // 1024 ids: 128 rows x 8 f32x4 segs
        int m = id >> 3, c = id & 7;
        xa[rep] = *(const f32x4*)&X[(size_t)(r0 + m) * 512 + c * 4];
    }
#pragma unroll
    for (int rep = 0; rep < 2; rep++) {
        int id = rep * 256 + tid;          // 512 ids: 128 rows x 4 k-segs
        int n = id >> 2, seg = id & 3;
        wbh[rep] = *(const bf16x8*)&Wh[(size_t)(c0 + n) * 512 + seg * 8];
        wbl[rep] = *(const bf16x8*)&Wl[(size_t)(c0 + n) * 512 + seg * 8];
    }

    for (int it = 0; it < 16; ++it) {
        // write staged regs to LDS (hi/lo conversion once per element)
#pragma unroll
        for (int rep = 0; rep < 4; rep++) {
            int id = rep * 256 + tid;
            int m = id >> 3, c = id & 7;
            f32x4 v = xa[rep];
            bf16x4 hh, ll;
#pragma unroll
            for (int e = 0; e < 4; e++) {
                bf16_t hv = (bf16_t)v[e];
                hh[e] = hv;
                ll[e] = (bf16_t)(v[e] - (float)hv);
            }
            *(bf16x4*)&Ah[m][c * 4] = hh;
            *(bf16x4*)&Al[m][c * 4] = ll;
        }
#pragma unroll
        for (int rep = 0; rep < 2; rep++) {
            int id = rep * 256 + tid;
            int n = id >> 2, seg = id & 3;
            *(bf16x8*)&Bh[n][seg * 8] = wbh[rep];
            *(bf16x8*)&Bl[n][seg * 8] = wbl[rep];
        }
        __syncthreads();

        // prefetch next K-chunk into regs (in flight under the MFMAs below)
        if (it < 15) {
            const int k0n = (it + 1) * 32;
#pragma unroll
            for (int rep = 0; rep < 4; rep++) {
                int id = rep * 256 + tid;
                int m = id >> 3, c = id & 7;
                xa[rep] = *(const f32x4*)&X[(size_t)(r0 + m) * 512 + k0n + c * 4];
            }
#pragma unroll
            for (int rep = 0; rep < 2; rep++) {
                int id = rep * 256 + tid;
                int n = id >> 2, seg = id & 3;
                wbh[rep] = *(const bf16x8*)&Wh[(size_t)(c0 + n) * 512 + k0n + seg * 8];
                wbl[rep] = *(const bf16x8*)&Wl[(size_t)(c0 + n) * 512 + k0n + seg * 8];
            }
        }

        // compute on LDS tile (single 32-wide K chunk)
        {
            bf16x8 bh[4], bl[4], ah[4], al[4];
#pragma unroll
            for (int nt = 0; nt < 4; nt++) {
                bh[nt] = *(const bf16x8*)&Bh[cb + nt * 16 + l16][quad * 8];
                bl[nt] = *(const bf16x8*)&Bl[cb + nt * 16 + l16][quad * 8];
            }
#pragma unroll
            for (int mt = 0; mt < 4; mt++) {
                ah[mt] = *(const bf16x8*)&Ah[rb + mt * 16 + l16][quad * 8];
                al[mt] = *(const bf16x8*)&Al[rb + mt * 16 + l16][quad * 8];
            }
#pragma unroll
            for (int mt = 0; mt < 4; mt++) {
#pragma unroll
                for (int nt = 0; nt < 4; nt++) {
                    acc[mt][nt] = __builtin_amdgcn_mfma_f32_16x16x32_bf16(ah[mt], bh[nt], acc[mt][nt], 0, 0, 0);
                    acc[mt][nt] = __builtin_amdgcn_mfma_f32_16x16x32_bf16(ah[mt], bl[nt], acc[mt][nt], 0, 0, 0);
                    acc[mt][nt] = __builtin_amdgcn_mfma_f32_16x16x32_bf16(al[mt], bh[nt], acc[mt][nt], 0, 0, 0);
                }
            }
        }
        __syncthreads();
    }

#pragma unroll
    for (int mt = 0; mt < 4; mt++) {
#pragma unroll
        for (int r = 0; r < 4; r++) {
            int row = r0 + rb + mt * 16 + quad * 4 + r;
#pragma unroll
            for (int nt = 0; nt < 4; nt++) {
                int col = c0 + cb + nt * 16 + l16;
                float y = acc[mt][nt][r] + (bias ? bias[col] : 0.f);
                int b = row >> 11, t = row & 2047;
                int h = col >> 6,  d = col & 63;
                if (z == 0) {
                    size_t idx = (((size_t)(b * Hh + h)) * Tt + t) * Dd + d;
                    QU[idx] = (bf16_t)(y + bias_u[col]);
                    QV[idx] = (bf16_t)(y + bias_v[col]);
                } else if (z == 1) {
                    size_t idx = (((size_t)(b * Hh + h)) * Tt + t) * Dd + d;
                    K16[idx] = (bf16_t)y;
                } else if (z == 2) {
                    // transposed: VT[bh][d][t]
                    size_t idx = (((size_t)(b * Hh + h)) * Dd + d) * Tt + t;
                    VT16[idx] = (bf16_t)y;
                } else {
                    size_t idx = (((size_t)(b * Hh + h)) * Tt + t) * Dd + d;
                    P16[idx] = (bf16_t)y;
                }
            }
        }
    }
}

// ---------------------------------------------------------------------------
// Out-projection GEMM, BK=32: OUT = CTX @ Wo + bo. 64x128 tiles, 512 blocks.
// LDS 30720 B -> 4 blocks/CU @ lb(256,4). Same K-chunk order as BK=64
// (kc sequential) => bit-identical accumulation.
// ---------------------------------------------------------------------------
__global__ __launch_bounds__(256, 4)
void out_gemm_kernel(const float* __restrict__ Xc, const bf16_t* __restrict__ WoT,
                     const float* __restrict__ bo, float* __restrict__ OUT)
{
    const bf16_t* Wh = WoT;
    const bf16_t* Wl = WoT + 262144;

    const int bx = blockIdx.x;             // 512 blocks: 128 mtiles x 4 ntiles
    const int r0 = (bx >> 2) * 64;
    const int c0 = (bx & 3) * 128;

    const int tid  = threadIdx.x;
    const int wave = tid >> 6;
    const int lane = tid & 63;
    const int quad = lane >> 4;
    const int l16  = lane & 15;
    const int rb = (wave >> 1) * 32;
    const int cb = (wave & 1) * 64;

    __shared__ __align__(16) bf16_t Ah[64][40];
    __shared__ __align__(16) bf16_t Al[64][40];
    __shared__ __align__(16) bf16_t Bh[128][40];
    __shared__ __align__(16) bf16_t Bl[128][40];

    f32x4 acc[2][4];
#pragma unroll
    for (int mt = 0; mt < 2; mt++)
#pragma unroll
        for (int nt = 0; nt < 4; nt++)
#pragma unroll
            for (int r = 0; r < 4; r++) acc[mt][nt][r] = 0.f;

    // staged-tile registers (BK=32)
    f32x4  xa[2];
    bf16x8 wbh[2], wbl[2];

    // prologue: K-chunk 0
#pragma unroll
    for (int rep = 0; rep < 2; rep++) {
        int id = rep * 256 + tid;          // 512 ids: 64 rows x 8 f32x4 segs
        int m = id >> 3, c = id & 7;
        xa[rep] = *(const f32x4*)&Xc[(size_t)(r0 + m) * 512 + c * 4];
    }
#pragma unroll
    for (int rep = 0; rep < 2; rep++) {
        int id = rep * 256 + tid;          // 512 ids: 128 rows x 4 k-segs
        int n = id >> 2, seg = id & 3;
        wbh[rep] = *(const bf16x8*)&Wh[(size_t)(c0 + n) * 512 + seg * 8];
        wbl[rep] = *(const bf16x8*)&Wl[(size_t)(c0 + n) * 512 + seg * 8];
    }

    for (int it = 0; it < 16; ++it) {
        // write staged regs to LDS
#pragma unroll
        for (int rep = 0; rep < 2; rep++) {
            int id = rep * 256 + tid;
            int m = id >> 3, c = id & 7;
            f32x4 v = xa[rep];
            bf16x4 hh, ll;
#pragma unroll
            for (int e = 0; e < 4; e++) {
                bf16_t hv = (bf16_t)v[e];
                hh[e] = hv;
                ll[e] = (bf16_t)(v[e] - (float)hv);
            }
            *(bf16x4*)&Ah[m][c * 4] = hh;
            *(bf16x4*)&Al[m][c * 4] = ll;
        }
#pragma unroll
        for (int rep = 0; rep < 2; rep++) {
            int id = rep * 256 + tid;
            int n = id >> 2, seg = id & 3;
            *(bf16x8*)&Bh[n][seg * 8] = wbh[rep];
            *(bf16x8*)&Bl[n][seg * 8] = wbl[rep];
        }
        __syncthreads();

        // prefetch next K-chunk
        if (it < 15) {
            const int k0n = (it + 1) * 32;
#pragma unroll
            for (int rep = 0; rep < 2; rep++) {
                int id = rep * 256 + tid;
                int m = id >> 3, c = id & 7;
                xa[rep] = *(const f32x4*)&Xc[(size_t)(r0 + m) * 512 + k0n + c * 4];
            }
#pragma unroll
            for (int rep = 0; rep < 2; rep++) {
                int id = rep * 256 + tid;
                int n = id >> 2, seg = id & 3;
                wbh[rep] = *(const bf16x8*)&Wh[(size_t)(c0 + n) * 512 + k0n + seg * 8];
                wbl[rep] = *(const bf16x8*)&Wl[(size_t)(c0 + n) * 512 + k0n + seg * 8];
            }
        }

        // compute (single 32-wide K chunk)
        {
            bf16x8 bh[4], bl[4], ah[2], al[2];
#pragma unroll
            for (int nt = 0; nt < 4; nt++) {
                bh[nt] = *(const bf16x8*)&Bh[cb + nt * 16 + l16][quad * 8];
                bl[nt] = *(const bf16x8*)&Bl[cb + nt * 16 + l16][quad * 8];
            }
#pragma unroll
            for (int mt = 0; mt < 2; mt++) {
                ah[mt] = *(const bf16x8*)&Ah[rb + mt * 16 + l16][quad * 8];
                al[mt] = *(const bf16x8*)&Al[rb + mt * 16 + l16][quad * 8];
            }
#pragma unroll
            for (int mt = 0; mt < 2; mt++) {
#pragma unroll
                for (int nt = 0; nt < 4; nt++) {
                    acc[mt][nt] = __builtin_amdgcn_mfma_f32_16x16x32_bf16(ah[mt], bh[nt], acc[mt][nt], 0, 0, 0);
                    acc[mt][nt] = __builtin_amdgcn_mfma_f32_16x16x32_bf16(ah[mt], bl[nt], acc[mt][nt], 0, 0, 0);
                    acc[mt][nt] = __builtin_amdgcn_mfma_f32_16x16x32_bf16(al[mt], bh[nt], acc[mt][nt], 0, 0, 0);
                }
            }
        }
        __syncthreads();
    }

#pragma unroll
    for (int mt = 0; mt < 2; mt++) {
#pragma unroll
        for (int r = 0; r < 4; r++) {
            int row = r0 + rb + mt * 16 + quad * 4 + r;
#pragma unroll
            for (int nt = 0; nt < 4; nt++) {
                int col = c0 + cb + nt * 16 + l16;
                OUT[(size_t)row * 512 + col] = acc[mt][nt][r] + bo[col];
            }
        }
    }
}

// ---------------------------------------------------------------------------
// Kernel 2: attention with T14 async-stage split (R17-exact, verified 204us).
// grid = (bh=32, itile=32). LDS 38912 (R12 layout).
// ---------------------------------------------------------------------------
struct Band { int d_hi, w1, prow1, w2, e_lo, c2_0, nct1, nct2; };

__device__ __forceinline__ Band mkband(int i0, int j0)
{
    Band b;
    int d_lo = i0 - (j0 + 63);
    b.d_hi = i0 + 63 - j0;
    b.w1 = 0; b.prow1 = 0;
    if (b.d_hi >= 0) {
        int b1 = d_lo > 0 ? d_lo : 0;
        b.w1 = b.d_hi - b1 + 1;
        b.prow1 = (Tt - 1) - b.d_hi;
    }
    int dmax2 = b.d_hi < -2 ? b.d_hi : -2;
    b.w2 = 0; b.e_lo = 0;
    if (d_lo <= dmax2) {
        b.e_lo = -dmax2 - 2;
        int e_hi = -d_lo - 2;
        b.w2 = e_hi - b.e_lo + 1;
    }
    b.c2_0 = b.d_hi + 2 + b.e_lo;
    b.nct1 = (b.w1 + 15) >> 4;
    b.nct2 = (b.w2 + 15) >> 4;
    return b;
}

__global__ __launch_bounds__(256, 4)
void attn_kernel(const bf16_t* __restrict__ QU, const bf16_t* __restrict__ QV,
                 const bf16_t* __restrict__ K16, const bf16_t* __restrict__ VT16,
                 const bf16_t* __restrict__ P16, float* __restrict__ CTX)
{
    const int bh = blockIdx.x;                 // XCD locality: linear%8 = bh%8
    const int i0 = blockIdx.y * 64;
    const int b = bh >> 3, h = bh & 7;
    const int tid = threadIdx.x;
    const int wave = tid >> 6;
    const int lane = tid & 63;
    const int quad = lane >> 4;
    const int l16 = lane & 15;

    const bf16_t* qu_g = QU + (size_t)bh * Tt * Dd;
    const bf16_t* qv_g = QV + (size_t)bh * Tt * Dd;
    const bf16_t* k_g  = K16 + (size_t)bh * Tt * Dd;
    const bf16_t* vt_g = VT16 + (size_t)bh * Dd * Tt;   // [d][t]
    const bf16_t* p_g  = P16 + (size_t)bh * Tt * Dd;

    __shared__ __align__(16) char smem[38912];
    bf16_t (*pA)[72]  = (bf16_t (*)[72])(smem);           // 128 rows (P band)
    bf16_t (*k_s)[72] = (bf16_t (*)[72])(smem + 18432);   // 64 rows
    bf16_t (*msw)[88] = (bf16_t (*)[88])(smem + 27648);   // 64 rows, strip-local

    const int off_w = 48 - wave * 16;          // strip-local = absolute - off_w
    const int cmin = 48 - wave * 16;           // absolute strip window
    const int cmax = 126 - wave * 16;

    // staging id decomposition (same for K and P paths)
    const int srow = tid >> 3;                 // 0..31
    const int sseg = tid & 7;                  // 0..7

    // A-operand fragments, direct global loads: A[m=l16][k=quad*8+e]
    const int qrow = i0 + wave * 16 + l16;
    const int qrow2 = (qrow + 1 > Tt - 1) ? (Tt - 1) : (qrow + 1);  // clamped row never gathered
    bf16x8 aq[2], av1[2], av2[2];
#pragma unroll
    for (int kc = 0; kc < 2; kc++) {
        aq[kc]  = *(const bf16x8*)(qu_g + (size_t)qrow  * Dd + kc * 32 + quad * 8);
        av1[kc] = *(const bf16x8*)(qv_g + (size_t)qrow  * Dd + kc * 32 + quad * 8);
        av2[kc] = *(const bf16x8*)(qv_g + (size_t)qrow2 * Dd + kc * 32 + quad * 8);
    }

    float lsum[4];
    f32x4 accO[4];
#pragma unroll
    for (int r = 0; r < 4; r++) lsum[r] = 0.f;
#pragma unroll
    for (int dt = 0; dt < 4; dt++)
#pragma unroll
        for (int r = 0; r < 4; r++) accO[dt][r] = 0.f;

    // --- T14 prefetch registers (named scalars; no arrays -> no scratch) ---
    f32x4 kr0, kr1, pr0, pr1, pr2, pr3;
    Band bp = mkband(i0, 0);
    {
        kr0 = *(const f32x4*)(k_g + (size_t)(0 + srow) * Dd + sseg * 8);
        kr1 = *(const f32x4*)(k_g + (size_t)(0 + srow + 32) * Dd + sseg * 8);
        int r0_ = srow,      s0 = (r0_ < bp.w1) ? bp.prow1 + r0_ : bp.e_lo + r0_ - bp.w1;
        int r1_ = srow + 32, s1 = (r1_ < bp.w1) ? bp.prow1 + r1_ : bp.e_lo + r1_ - bp.w1;
        int r2_ = srow + 64, s2 = (r2_ < bp.w1) ? bp.prow1 + r2_ : bp.e_lo + r2_ - bp.w1;
        int r3_ = srow + 96, s3 = (r3_ < bp.w1) ? bp.prow1 + r3_ : bp.e_lo + r3_ - bp.w1;
        if (s0 > Tt - 1) s0 = Tt - 1;
        if (s1 > Tt - 1) s1 = Tt - 1;
        if (s2 > Tt - 1) s2 = Tt - 1;
        if (s3 > Tt - 1) s3 = Tt - 1;
        pr0 = *(const f32x4*)(p_g + (size_t)s0 * Dd + sseg * 8);
        pr1 = *(const f32x4*)(p_g + (size_t)s1 * Dd + sseg * 8);
        pr2 = *(const f32x4*)(p_g + (size_t)s2 * Dd + sseg * 8);
        pr3 = *(const f32x4*)(p_g + (size_t)s3 * Dd + sseg * 8);
    }

    for (int j0 = 0; j0 < Tt; j0 += 64) {
        const Band bc = bp;

        // write prefetched regs to LDS (same addresses/guards as staged path)
        *(f32x4*)&k_s[srow][sseg * 8]      = kr0;
        *(f32x4*)&k_s[srow + 32][sseg * 8] = kr1;
        {
            int wtot = bc.w1 + bc.w2;
            if (srow < wtot)      *(f32x4*)&pA[srow][sseg * 8]      = pr0;
            if (srow + 32 < wtot) *(f32x4*)&pA[srow + 32][sseg * 8] = pr1;
            if (srow + 64 < wtot) *(f32x4*)&pA[srow + 64][sseg * 8] = pr2;
            if (srow + 96 < wtot) *(f32x4*)&pA[srow + 96][sseg * 8] = pr3;
        }
        __syncthreads();

        // issue next tile's K/P loads now; they fly under the compute below
        if (j0 + 64 < Tt) {
            bp = mkband(i0, j0 + 64);
            kr0 = *(const f32x4*)(k_g + (size_t)(j0 + 64 + srow) * Dd + sseg * 8);
            kr1 = *(const f32x4*)(k_g + (size_t)(j0 + 64 + srow + 32) * Dd + sseg * 8);
            int r0_ = srow,      s0 = (r0_ < bp.w1) ? bp.prow1 + r0_ : bp.e_lo + r0_ - bp.w1;
            int r1_ = srow + 32, s1 = (r1_ < bp.w1) ? bp.prow1 + r1_ : bp.e_lo + r1_ - bp.w1;
            int r2_ = srow + 64, s2 = (r2_ < bp.w1) ? bp.prow1 + r2_ : bp.e_lo + r2_ - bp.w1;
            int r3_ = srow + 96, s3 = (r3_ < bp.w1) ? bp.prow1 + r3_ : bp.e_lo + r3_ - bp.w1;
            if (s0 > Tt - 1) s0 = Tt - 1;
            if (s1 > Tt - 1) s1 = Tt - 1;
            if (s2 > Tt - 1) s2 = Tt - 1;
            if (s3 > Tt - 1) s3 = Tt - 1;
            pr0 = *(const f32x4*)(p_g + (size_t)s0 * Dd + sseg * 8);
            pr1 = *(const f32x4*)(p_g + (size_t)s1 * Dd + sseg * 8);
            pr2 = *(const f32x4*)(p_g + (size_t)s2 * Dd + sseg * 8);
            pr3 = *(const f32x4*)(p_g + (size_t)s3 * Dd + sseg * 8);
        }

        // content scores
        f32x4 accS[4];
#pragma unroll
        for (int nt = 0; nt < 4; nt++) {
            f32x4 acc = {0.f, 0.f, 0.f, 0.f};
#pragma unroll
            for (int kc = 0; kc < 2; kc++) {
                bf16x8 bk8 = *(const bf16x8*)&k_s[nt * 16 + l16][kc * 32 + quad * 8];
                acc = __builtin_amdgcn_mfma_f32_16x16x32_bf16(aq[kc], bk8, acc, 0, 0, 0);
            }
            accS[nt] = acc;
        }

        // banded pos matmul -> strip-local skewed store (wave-private)
        for (int ct = 0; ct < bc.nct1 + bc.nct2; ct++) {
            bool b2 = ct >= bc.nct1;
            int rb_ = b2 ? (bc.w1 + (ct - bc.nct1) * 16) : (ct * 16);
            int cb_ = b2 ? (bc.c2_0 + (ct - bc.nct1) * 16) : (ct * 16);
            if (cb_ > cmax || cb_ + 15 < cmin) continue;
            f32x4 acc = {0.f, 0.f, 0.f, 0.f};
#pragma unroll
            for (int kc = 0; kc < 2; kc++) {
                bf16x8 bp8 = *(const bf16x8*)&pA[rb_ + l16][kc * 32 + quad * 8];
                acc = b2 ? __builtin_amdgcn_mfma_f32_16x16x32_bf16(av2[kc], bp8, acc, 0, 0, 0)
                         : __builtin_amdgcn_mfma_f32_16x16x32_bf16(av1[kc], bp8, acc, 0, 0, 0);
            }
            int colp = cb_ + l16 - off_w;          // strip-local
            if ((unsigned)colp < 80u) {
#pragma unroll
                for (int r = 0; r < 4; r++)
                    msw[wave * 16 + quad * 4 + r][colp] = (bf16_t)acc[r];
            }
        }
        // zero column for dd == -1 (strip-local)
        {
            int zcl = bc.d_hi + 1 - off_w;
            if ((unsigned)zcl < 80u && quad == 0)
                msw[wave * 16 + l16][zcl] = (bf16_t)0.f;
        }

        // gather all 16 (no aliasing stores in between), then write weights
        float wv[4][4];
#pragma unroll
        for (int nt = 0; nt < 4; nt++) {
#pragma unroll
            for (int r = 0; r < 4; r++) {
                float pos = (float)msw[wave * 16 + quad * 4 + r]
                                    [nt * 16 + l16 + 15 - (quad * 4 + r)];
                float x = accS[nt][r] + pos;
                float a = fminf(fmaf(x, 0.18033688f, -17.3123405f), 120.0f);
                float w = exp2f(a);
                lsum[r] += w;
                wv[nt][r] = w;
            }
        }
#pragma unroll
        for (int nt = 0; nt < 4; nt++)
#pragma unroll
            for (int r = 0; r < 4; r++)
                msw[wave * 16 + quad * 4 + r][nt * 16 + l16] = (bf16_t)wv[nt][r];

        // O += W @ V : A from own msw strip, B direct from VT ([d][t])
#pragma unroll
        for (int kc = 0; kc < 2; kc++) {
            bf16x8 aw = *(const bf16x8*)&msw[wave * 16 + l16][kc * 32 + quad * 8];
#pragma unroll
            for (int dt = 0; dt < 4; dt++) {
                bf16x8 bv8 = *(const bf16x8*)(vt_g + (size_t)(dt * 16 + l16) * Tt + j0 + kc * 32 + quad * 8);
                accO[dt] = __builtin_amdgcn_mfma_f32_16x16x32_bf16(aw, bv8, accO[dt], 0, 0, 0);
            }
        }
        __syncthreads();  // protect k_s/pA before next write phase
    }

#pragma unroll
    for (int r = 0; r < 4; r++) {
#pragma unroll
        for (int off = 1; off < 16; off <<= 1) lsum[r] += __shfl_xor(lsum[r], off, 64);
    }

#pragma unroll
    for (int r = 0; r < 4; r++) {
        int il = wave * 16 + quad * 4 + r;
        int ig = i0 + il;
        float inv = 1.0f / lsum[r];
#pragma unroll
        for (int dt = 0; dt < 4; dt++) {
            CTX[((size_t)(b * Tt + ig)) * Cc + h * Dd + dt * 16 + l16] = accO[dt][r] * inv;
        }
    }
}

// ---------------------------------------------------------------------------
extern "C" void kernel_launch(void* const* d_in, const int* in_sizes, int n_in,
                              void* d_out, int out_size, void* d_ws, size_t ws_size,
                              hipStream_t stream)
{
    const float* query = (const float*)d_in[0];
    const float* key   = (const float*)d_in[1];
    const float* value = (const float*)d_in[2];
    const float* pemb  = (const float*)d_in[3];
    const float* Wq    = (const float*)d_in[4];
    const float* bq    = (const float*)d_in[5];
    const float* Wk    = (const float*)d_in[6];
    const float* bk    = (const float*)d_in[7];
    const float* Wv    = (const float*)d_in[8];
    const float* bv    = (const float*)d_in[9];
    const float* Wpos  = (const float*)d_in[10];
    const float* pbu   = (const float*)d_in[11];
    const float* pbv   = (const float*)d_in[12];
    const float* Wo    = (const float*)d_in[13];
    const float* bo    = (const float*)d_in[14];

    const size_t NE = (size_t)Bb * Hh * Tt * Dd;  // 4,194,304 per tensor
    bf16_t* QU   = (bf16_t*)d_ws;
    bf16_t* QV   = QU + NE;
    bf16_t* K16  = QV + NE;
    bf16_t* VT16 = K16 + NE;
    bf16_t* P16  = VT16 + NE;
    float*  CTX  = (float*)(P16 + NE);            // ws >= 56 MB (unchanged)

    // W^T hi/lo planes overlaid on dead regions (no extra workspace):
    //  - WT4 (Wq,Wk,Wv,Wpos; 4 MB) in CTX region: dead until attn writes CTX.
    //  - WoT (1 MB) in QU region: written AFTER attn (QU dead by then).
    bf16_t* WT4 = (bf16_t*)CTX;
    bf16_t* WoT = (bf16_t*)QU;

    // prepass A: Wq/Wk/Wv/Wpos -> transposed hi/lo bf16 planes
    wsplit_kernel<<<dim3(64, 4), 256, 0, stream>>>(Wq, Wk, Wv, Wpos, Wo, WT4, WoT, -1);

    // QKVP projections (z = blockIdx.z)
    split_gemm_kernel<<<dim3(256, 1, 4), 256, 0, stream>>>(
        query, key, value, pemb, WT4,
        bq, bk, bv, pbu, pbv, QU, QV, K16, VT16, P16);

    attn_kernel<<<dim3(32, 32), 256, 0, stream>>>(QU, QV, K16, VT16, P16, CTX);

    // prepass B: Wo -> WoT (QU region now dead)
    wsplit_kernel<<<dim3(64, 1), 256, 0, stream>>>(Wq, Wk, Wv, Wpos, Wo, WT4, WoT, 4);

    // output projection: 64x128 tiles, 512 blocks, BK=32
    out_gemm_kernel<<<dim3(512), 256, 0, stream>>>(CTX, WoT, bo, (float*)d_out);
}

// Round 12
// 408.121 us; speedup vs baseline: 1.3418x; 1.0078x over previous
//
#include <hip/hip_runtime.h>

// ---------------------------------------------------------------------------
// RelPositionMultiHeadedAttention (Conformer / Transformer-XL rel-shift)
// B=4, T=2048, C=512, H=8, D=64
//
// R20: B-staging via __builtin_amdgcn_global_load_lds (width 16) in both
// GEMMs (attn/wsplit = R19-exact).
//  - Unpadded [128][32] bf16 tiles: staging write offset = tid*16 (exactly
//    the wave-uniform base + lane*16 pattern gload_lds requires, m104);
//    fragment reads become contiguous 1KB/wave => zero bank conflicts.
//  - B double-buffered: next tile's gloads issue post-barrier, land during
//    compute, drained by the end-of-compute barrier.
//  - Bytes identical (straight copy of same bf16 data) => bit-identical
//    output; absmax must stay exactly 0.005859375.
//  - QKVP LDS 48KB (3 blocks/CU); out_gemm LDS 40KB (4 blocks/CU).
// ---------------------------------------------------------------------------

#define Bb 4
#define Tt 2048
#define Cc 512
#define Hh 8
#define Dd 64

typedef __bf16 bf16_t;
typedef __bf16 bf16x8 __attribute__((ext_vector_type(8)));
typedef __bf16 bf16x4 __attribute__((ext_vector_type(4)));
typedef float  f32x4  __attribute__((ext_vector_type(4)));

__device__ __forceinline__ void gload16(const bf16_t* g, bf16_t* l)
{
    // async global->LDS copy, 16B per lane; LDS dest = wave base + lane*16
    __builtin_amdgcn_global_load_lds(g, l, 16, 0, 0);
}

// ---------------------------------------------------------------------------
// Prepass: WT_hi[n][k], WT_lo[n][k] bf16 from W[k][n] f32. (R19-exact)
// ---------------------------------------------------------------------------
__global__ __launch_bounds__(256, 4)
void wsplit_kernel(const float* __restrict__ Wq, const float* __restrict__ Wk,
                   const float* __restrict__ Wv, const float* __restrict__ Wp,
                   const float* __restrict__ Wo,
                   bf16_t* __restrict__ WT4, bf16_t* __restrict__ WoT, int mode)
{
    const int w = (mode < 0) ? (int)blockIdx.y : 4;
    const float* W = (w == 0) ? Wq : (w == 1) ? Wk : (w == 2) ? Wv : (w == 3) ? Wp : Wo;
    bf16_t* dh = (w == 4) ? WoT : WT4 + (size_t)w * 2 * 262144;
    bf16_t* dl = dh + 262144;

    const int tile = blockIdx.x;           // 64 tiles of 64x64
    const int k0 = (tile >> 3) * 64;
    const int n0 = (tile & 7) * 64;
    const int tid = threadIdx.x;

    __shared__ bf16_t th[64][66];
    __shared__ bf16_t tl[64][66];

#pragma unroll
    for (int rep = 0; rep < 4; rep++) {
        int id = rep * 256 + tid;          // 1024 ids: 64 k-rows x 16 f32x4 segs
        int kk = id >> 4, ns = id & 15;
        f32x4 v = *(const f32x4*)&W[(size_t)(k0 + kk) * 512 + n0 + ns * 4];
#pragma unroll
        for (int e = 0; e < 4; e++) {
            bf16_t h = (bf16_t)v[e];
            th[kk][ns * 4 + e] = h;
            tl[kk][ns * 4 + e] = (bf16_t)(v[e] - (float)h);
        }
    }
    __syncthreads();
#pragma unroll
    for (int rep = 0; rep < 2; rep++) {
        int id = rep * 256 + tid;          // 512 ids: 64 n-rows x 8 k-segs
        int nn = id >> 3, ks = id & 7;
        bf16x8 hv, lv;
#pragma unroll
        for (int j = 0; j < 8; j++) { hv[j] = th[ks * 8 + j][nn]; lv[j] = tl[ks * 8 + j][nn]; }
        *(bf16x8*)&dh[(size_t)(n0 + nn) * 512 + k0 + ks * 8] = hv;
        *(bf16x8*)&dl[(size_t)(n0 + nn) * 512 + k0 + ks * 8] = lv;
    }
}

// ---------------------------------------------------------------------------
// QKVP split-bf16 GEMM, BK=32, B via global_load_lds into unpadded dbuf.
// z = blockIdx.z: 0=Q(->QU,QV) 1=K 2=V(->VT) 3=P.
// ---------------------------------------------------------------------------
__global__ __launch_bounds__(256, 3)
void split_gemm_kernel(const float* __restrict__ Xq, const float* __restrict__ Xk,
                       const float* __restrict__ Xv, const float* __restrict__ Xp,
                       const bf16_t* __restrict__ WT4,
                       const float* __restrict__ bq, const float* __restrict__ bk,
                       const float* __restrict__ bv,
                       const float* __restrict__ bias_u, const float* __restrict__ bias_v,
                       bf16_t* __restrict__ QU, bf16_t* __restrict__ QV,
                       bf16_t* __restrict__ K16, bf16_t* __restrict__ VT16,
                       bf16_t* __restrict__ P16)
{
    const int z = blockIdx.z;
    const float* X    = (z == 0) ? Xq : (z == 1) ? Xk : (z == 2) ? Xv : Xp;
    const bf16_t* Wh  = WT4 + (size_t)z * 2 * 262144;
    const bf16_t* Wl  = Wh + 262144;
    const float* bias = (z == 0) ? bq : (z == 1) ? bk : (z == 2) ? bv : nullptr;

    const int bx = blockIdx.x;
    const int g  = bx >> 3, x8 = bx & 7;
    const int mtile = (g >> 2) * 8 + x8;   // 0..63
    const int ntile = g & 3;               // 0..3
    const int r0 = mtile * 128;
    const int c0 = ntile * 128;

    const int tid  = threadIdx.x;
    const int wave = tid >> 6;
    const int lane = tid & 63;
    const int quad = lane >> 4;
    const int l16  = lane & 15;
    const int rb = (wave >> 1) * 64;
    const int cb = (wave & 1) * 64;

    // Unpadded tiles: row = 64B => fragment reads are contiguous 1KB/wave
    // (conflict-free); staging write offset = tid*16 (gload_lds pattern).
    __shared__ __align__(16) bf16_t Ah[128][32];
    __shared__ __align__(16) bf16_t Al[128][32];
    __shared__ __align__(16) bf16_t Bh[2][128][32];
    __shared__ __align__(16) bf16_t Bl[2][128][32];

    f32x4 acc[4][4];
#pragma unroll
    for (int mt = 0; mt < 4; mt++)
#pragma unroll
        for (int nt = 0; nt < 4; nt++)
#pragma unroll
            for (int r = 0; r < 4; r++) acc[mt][nt][r] = 0.f;

    // staging id decomposition
    const int am = tid >> 3, ac = tid & 7;     // A: row (+32/rep), f32x4 seg
    const int brow = tid >> 2, bseg = tid & 3; // B: row (+64/rep), 16B seg

    f32x4 xa[4];

    // prologue: A(0) -> regs; B(0) -> LDS buf0 via gload_lds
#pragma unroll
    for (int rep = 0; rep < 4; rep++)
        xa[rep] = *(const f32x4*)&X[(size_t)(r0 + am + rep * 32) * 512 + ac * 4];
#pragma unroll
    for (int rep = 0; rep < 2; rep++) {
        gload16(&Wh[(size_t)(c0 + rep * 64 + brow) * 512 + bseg * 8],
                &Bh[0][rep * 64 + brow][bseg * 8]);
        gload16(&Wl[(size_t)(c0 + rep * 64 + brow) * 512 + bseg * 8],
                &Bl[0][rep * 64 + brow][bseg * 8]);
    }

    for (int it = 0; it < 16; ++it) {
        // WRITE A(it): hi/lo conversion once per element
#pragma unroll
        for (int rep = 0; rep < 4; rep++) {
            f32x4 v = xa[rep];
            bf16x4 hh, ll;
#pragma unroll
            for (int e = 0; e < 4; e++) {
                bf16_t hv = (bf16_t)v[e];
                hh[e] = hv;
                ll[e] = (bf16_t)(v[e] - (float)hv);
            }
            *(bf16x4*)&Ah[am + rep * 32][ac * 4] = hh;
            *(bf16x4*)&Al[am + rep * 32][ac * 4] = ll;
        }
        __syncthreads();   // A visible; B(it) gloads drained

        // issue next-tile loads; they land during the compute below
        if (it < 15) {
            const int k0n = (it + 1) * 32;
            const int nb = (it + 1) & 1;
#pragma unroll
            for (int rep = 0; rep < 2; rep++) {
                gload16(&Wh[(size_t)(c0 + rep * 64 + brow) * 512 + k0n + bseg * 8],
                        &Bh[nb][rep * 64 + brow][bseg * 8]);
                gload16(&Wl[(size_t)(c0 + rep * 64 + brow) * 512 + k0n + bseg * 8],
                        &Bl[nb][rep * 64 + brow][bseg * 8]);
            }
#pragma unroll
            for (int rep = 0; rep < 4; rep++)
                xa[rep] = *(const f32x4*)&X[(size_t)(r0 + am + rep * 32) * 512 + k0n + ac * 4];
        }

        // COMPUTE: A planes + B buf[it&1]
        {
            const int cbuf = it & 1;
            bf16x8 bh[4], bl[4], ah[4], al[4];
#pragma unroll
            for (int nt = 0; nt < 4; nt++) {
                bh[nt] = *(const bf16x8*)&Bh[cbuf][cb + nt * 16 + l16][quad * 8];
                bl[nt] = *(const bf16x8*)&Bl[cbuf][cb + nt * 16 + l16][quad * 8];
            }
#pragma unroll
            for (int mt = 0; mt < 4; mt++) {
                ah[mt] = *(const bf16x8*)&Ah[rb + mt * 16 + l16][quad * 8];
                al[mt] = *(const bf16x8*)&Al[rb + mt * 16 + l16][quad * 8];
            }
#pragma unroll
            for (int mt = 0; mt < 4; mt++) {
#pragma unroll
                for (int nt = 0; nt < 4; nt++) {
                    acc[mt][nt] = __builtin_amdgcn_mfma_f32_16x16x32_bf16(ah[mt], bh[nt], acc[mt][nt], 0, 0, 0);
                    acc[mt][nt] = __builtin_amdgcn_mfma_f32_16x16x32_bf16(ah[mt], bl[nt], acc[mt][nt], 0, 0, 0);
                    acc[mt][nt] = __builtin_amdgcn_mfma_f32_16x16x32_bf16(al[mt], bh[nt], acc[mt][nt], 0, 0, 0);
                }
            }
        }
        __syncthreads();   // WAR on A; drains B(it+1)/A(it+1) after compute
    }

#pragma unroll
    for (int mt = 0; mt < 4; mt++) {
#pragma unroll
        for (int r = 0; r < 4; r++) {
            int row = r0 + rb + mt * 16 + quad * 4 + r;
#pragma unroll
            for (int nt = 0; nt < 4; nt++) {
                int col = c0 + cb + nt * 16 + l16;
                float y = acc[mt][nt][r] + (bias ? bias[col] : 0.f);
                int b = row >> 11, t = row & 2047;
                int h = col >> 6,  d = col & 63;
                if (z == 0) {
                    size_t idx = (((size_t)(b * Hh + h)) * Tt + t) * Dd + d;
                    QU[idx] = (bf16_t)(y + bias_u[col]);
                    QV[idx] = (bf16_t)(y + bias_v[col]);
                } else if (z == 1) {
                    size_t idx = (((size_t)(b * Hh + h)) * Tt + t) * Dd + d;
                    K16[idx] = (bf16_t)y;
                } else if (z == 2) {
                    // transposed: VT[bh][d][t]
                    size_t idx = (((size_t)(b * Hh + h)) * Dd + d) * Tt + t;
                    VT16[idx] = (bf16_t)y;
                } else {
                    size_t idx = (((size_t)(b * Hh + h)) * Tt + t) * Dd + d;
                    P16[idx] = (bf16_t)y;
                }
            }
        }
    }
}

// ---------------------------------------------------------------------------
// Out-projection GEMM, BK=32, B via global_load_lds (same transform).
// 64x128 tiles, 512 blocks; LDS 40KB -> 4 blocks/CU.
// ---------------------------------------------------------------------------
__global__ __launch_bounds__(256, 4)
void out_gemm_kernel(const float* __restrict__ Xc, const bf16_t* __restrict__ WoT,
                     const float* __restrict__ bo, float* __restrict__ OUT)
{
    const bf16_t* Wh = WoT;
    const bf16_t* Wl = WoT + 262144;

    const int bx = blockIdx.x;             // 512 blocks: 128 mtiles x 4 ntiles
    const int r0 = (bx >> 2) * 64;
    const int c0 = (bx & 3) * 128;

    const int tid  = threadIdx.x;
    const int wave = tid >> 6;
    const int lane = tid & 63;
    const int quad = lane >> 4;
    const int l16  = lane & 15;
    const int rb = (wave >> 1) * 32;
    const int cb = (wave & 1) * 64;

    __shared__ __align__(16) bf16_t Ah[64][32];
    __shared__ __align__(16) bf16_t Al[64][32];
    __shared__ __align__(16) bf16_t Bh[2][128][32];
    __shared__ __align__(16) bf16_t Bl[2][128][32];

    f32x4 acc[2][4];
#pragma unroll
    for (int mt = 0; mt < 2; mt++)
#pragma unroll
        for (int nt = 0; nt < 4; nt++)
#pragma unroll
            for (int r = 0; r < 4; r++) acc[mt][nt][r] = 0.f;

    const int am = tid >> 3, ac = tid & 7;     // A: row (+32/rep), f32x4 seg
    const int brow = tid >> 2, bseg = tid & 3; // B: row (+64/rep), 16B seg

    f32x4 xa[2];

    // prologue: A(0) -> regs; B(0) -> buf0
#pragma unroll
    for (int rep = 0; rep < 2; rep++)
        xa[rep] = *(const f32x4*)&Xc[(size_t)(r0 + am + rep * 32) * 512 + ac * 4];
#pragma unroll
    for (int rep = 0; rep < 2; rep++) {
        gload16(&Wh[(size_t)(c0 + rep * 64 + brow) * 512 + bseg * 8],
                &Bh[0][rep * 64 + brow][bseg * 8]);
        gload16(&Wl[(size_t)(c0 + rep * 64 + brow) * 512 + bseg * 8],
                &Bl[0][rep * 64 + brow][bseg * 8]);
    }

    for (int it = 0; it < 16; ++it) {
        // WRITE A(it)
#pragma unroll
        for (int rep = 0; rep < 2; rep++) {
            f32x4 v = xa[rep];
            bf16x4 hh, ll;
#pragma unroll
            for (int e = 0; e < 4; e++) {
                bf16_t hv = (bf16_t)v[e];
                hh[e] = hv;
                ll[e] = (bf16_t)(v[e] - (float)hv);
            }
            *(bf16x4*)&Ah[am + rep * 32][ac * 4] = hh;
            *(bf16x4*)&Al[am + rep * 32][ac * 4] = ll;
        }
        __syncthreads();

        if (it < 15) {
            const int k0n = (it + 1) * 32;
            const int nb = (it + 1) & 1;
#pragma unroll
            for (int rep = 0; rep < 2; rep++) {
                gload16(&Wh[(size_t)(c0 + rep * 64 + brow) * 512 + k0n + bseg * 8],
                        &Bh[nb][rep * 64 + brow][bseg * 8]);
                gload16(&Wl[(size_t)(c0 + rep * 64 + brow) * 512 + k0n + bseg * 8],
                        &Bl[nb][rep * 64 + brow][bseg * 8]);
            }
#pragma unroll
            for (int rep = 0; rep < 2; rep++)
                xa[rep] = *(const f32x4*)&Xc[(size_t)(r0 + am + rep * 32) * 512 + k0n + ac * 4];
        }

        // COMPUTE
        {
            const int cbuf = it & 1;
            bf16x8 bh[4], bl[4], ah[2], al[2];
#pragma unroll
            for (int nt = 0; nt < 4; nt++) {
                bh[nt] = *(const bf16x8*)&Bh[cbuf][cb + nt * 16 + l16][quad * 8];
                bl[nt] = *(const bf16x8*)&Bl[cbuf][cb + nt * 16 + l16][quad * 8];
            }
#pragma unroll
            for (int mt = 0; mt < 2; mt++) {
                ah[mt] = *(const bf16x8*)&Ah[rb + mt * 16 + l16][quad * 8];
                al[mt] = *(const bf16x8*)&Al[rb + mt * 16 + l16][quad * 8];
            }
#pragma unroll
            for (int mt = 0; mt < 2; mt++) {
#pragma unroll
                for (int nt = 0; nt < 4; nt++) {
                    acc[mt][nt] = __builtin_amdgcn_mfma_f32_16x16x32_bf16(ah[mt], bh[nt], acc[mt][nt], 0, 0, 0);
                    acc[mt][nt] = __builtin_amdgcn_mfma_f32_16x16x32_bf16(ah[mt], bl[nt], acc[mt][nt], 0, 0, 0);
                    acc[mt][nt] = __builtin_amdgcn_mfma_f32_16x16x32_bf16(al[mt], bh[nt], acc[mt][nt], 0, 0, 0);
                }
            }
        }
        __syncthreads();
    }

#pragma unroll
    for (int mt = 0; mt < 2; mt++) {
#pragma unroll
        for (int r = 0; r < 4; r++) {
            int row = r0 + rb + mt * 16 + quad * 4 + r;
#pragma unroll
            for (int nt = 0; nt < 4; nt++) {
                int col = c0 + cb + nt * 16 + l16;
                OUT[(size_t)row * 512 + col] = acc[mt][nt][r] + bo[col];
            }
        }
    }
}

// ---------------------------------------------------------------------------
// Kernel 2: attention with T14 async-stage split (R17/R19-exact, ~203us).
// grid = (bh=32, itile=32). LDS 38912 (R12 layout).
// ---------------------------------------------------------------------------
struct Band { int d_hi, w1, prow1, w2, e_lo, c2_0, nct1, nct2; };

__device__ __forceinline__ Band mkband(int i0, int j0)
{
    Band b;
    int d_lo = i0 - (j0 + 63);
    b.d_hi = i0 + 63 - j0;
    b.w1 = 0; b.prow1 = 0;
    if (b.d_hi >= 0) {
        int b1 = d_lo > 0 ? d_lo : 0;
        b.w1 = b.d_hi - b1 + 1;
        b.prow1 = (Tt - 1) - b.d_hi;
    }
    int dmax2 = b.d_hi < -2 ? b.d_hi : -2;
    b.w2 = 0; b.e_lo = 0;
    if (d_lo <= dmax2) {
        b.e_lo = -dmax2 - 2;
        int e_hi = -d_lo - 2;
        b.w2 = e_hi - b.e_lo + 1;
    }
    b.c2_0 = b.d_hi + 2 + b.e_lo;
    b.nct1 = (b.w1 + 15) >> 4;
    b.nct2 = (b.w2 + 15) >> 4;
    return b;
}

__global__ __launch_bounds__(256, 4)
void attn_kernel(const bf16_t* __restrict__ QU, const bf16_t* __restrict__ QV,
                 const bf16_t* __restrict__ K16, const bf16_t* __restrict__ VT16,
                 const bf16_t* __restrict__ P16, float* __restrict__ CTX)
{
    const int bh = blockIdx.x;                 // XCD locality: linear%8 = bh%8
    const int i0 = blockIdx.y * 64;
    const int b = bh >> 3, h = bh & 7;
    const int tid = threadIdx.x;
    const int wave = tid >> 6;
    const int lane = tid & 63;
    const int quad = lane >> 4;
    const int l16 = lane & 15;

    const bf16_t* qu_g = QU + (size_t)bh * Tt * Dd;
    const bf16_t* qv_g = QV + (size_t)bh * Tt * Dd;
    const bf16_t* k_g  = K16 + (size_t)bh * Tt * Dd;
    const bf16_t* vt_g = VT16 + (size_t)bh * Dd * Tt;   // [d][t]
    const bf16_t* p_g  = P16 + (size_t)bh * Tt * Dd;

    __shared__ __align__(16) char smem[38912];
    bf16_t (*pA)[72]  = (bf16_t (*)[72])(smem);           // 128 rows (P band)
    bf16_t (*k_s)[72] = (bf16_t (*)[72])(smem + 18432);   // 64 rows
    bf16_t (*msw)[88] = (bf16_t (*)[88])(smem + 27648);   // 64 rows, strip-local

    const int off_w = 48 - wave * 16;          // strip-local = absolute - off_w
    const int cmin = 48 - wave * 16;           // absolute strip window
    const int cmax = 126 - wave * 16;

    // staging id decomposition (same for K and P paths)
    const int srow = tid >> 3;                 // 0..31
    const int sseg = tid & 7;                  // 0..7

    // A-operand fragments, direct global loads: A[m=l16][k=quad*8+e]
    const int qrow = i0 + wave * 16 + l16;
    const int qrow2 = (qrow + 1 > Tt - 1) ? (Tt - 1) : (qrow + 1);  // clamped row never gathered
    bf16x8 aq[2], av1[2], av2[2];
#pragma unroll
    for (int kc = 0; kc < 2; kc++) {
        aq[kc]  = *(const bf16x8*)(qu_g + (size_t)qrow  * Dd + kc * 32 + quad * 8);
        av1[kc] = *(const bf16x8*)(qv_g + (size_t)qrow  * Dd + kc * 32 + quad * 8);
        av2[kc] = *(const bf16x8*)(qv_g + (size_t)qrow2 * Dd + kc * 32 + quad * 8);
    }

    float lsum[4];
    f32x4 accO[4];
#pragma unroll
    for (int r = 0; r < 4; r++) lsum[r] = 0.f;
#pragma unroll
    for (int dt = 0; dt < 4; dt++)
#pragma unroll
        for (int r = 0; r < 4; r++) accO[dt][r] = 0.f;

    // --- T14 prefetch registers (named scalars; no arrays -> no scratch) ---
    f32x4 kr0, kr1, pr0, pr1, pr2, pr3;
    Band bp = mkband(i0, 0);
    {
        kr0 = *(const f32x4*)(k_g + (size_t)(0 + srow) * Dd + sseg * 8);
        kr1 = *(const f32x4*)(k_g + (size_t)(0 + srow + 32) * Dd + sseg * 8);
        int r0_ = srow,      s0 = (r0_ < bp.w1) ? bp.prow1 + r0_ : bp.e_lo + r0_ - bp.w1;
        int r1_ = srow + 32, s1 = (r1_ < bp.w1) ? bp.prow1 + r1_ : bp.e_lo + r1_ - bp.w1;
        int r2_ = srow + 64, s2 = (r2_ < bp.w1) ? bp.prow1 + r2_ : bp.e_lo + r2_ - bp.w1;
        int r3_ = srow + 96, s3 = (r3_ < bp.w1) ? bp.prow1 + r3_ : bp.e_lo + r3_ - bp.w1;
        if (s0 > Tt - 1) s0 = Tt - 1;
        if (s1 > Tt - 1) s1 = Tt - 1;
        if (s2 > Tt - 1) s2 = Tt - 1;
        if (s3 > Tt - 1) s3 = Tt - 1;
        pr0 = *(const f32x4*)(p_g + (size_t)s0 * Dd + sseg * 8);
        pr1 = *(const f32x4*)(p_g + (size_t)s1 * Dd + sseg * 8);
        pr2 = *(const f32x4*)(p_g + (size_t)s2 * Dd + sseg * 8);
        pr3 = *(const f32x4*)(p_g + (size_t)s3 * Dd + sseg * 8);
    }

    for (int j0 = 0; j0 < Tt; j0 += 64) {
        const Band bc = bp;

        // write prefetched regs to LDS (same addresses/guards as staged path)
        *(f32x4*)&k_s[srow][sseg * 8]      = kr0;
        *(f32x4*)&k_s[srow + 32][sseg * 8] = kr1;
        {
            int wtot = bc.w1 + bc.w2;
            if (srow < wtot)      *(f32x4*)&pA[srow][sseg * 8]      = pr0;
            if (srow + 32 < wtot) *(f32x4*)&pA[srow + 32][sseg * 8] = pr1;
            if (srow + 64 < wtot) *(f32x4*)&pA[srow + 64][sseg * 8] = pr2;
            if (srow + 96 < wtot) *(f32x4*)&pA[srow + 96][sseg * 8] = pr3;
        }
        __syncthreads();

        // issue next tile's K/P loads now; they fly under the compute below
        if (j0 + 64 < Tt) {
            bp = mkband(i0, j0 + 64);
            kr0 = *(const f32x4*)(k_g + (size_t)(j0 + 64 + srow) * Dd + sseg * 8);
            kr1 = *(const f32x4*)(k_g + (size_t)(j0 + 64 + srow + 32) * Dd + sseg * 8);
            int r0_ = srow,      s0 = (r0_ < bp.w1) ? bp.prow1 + r0_ : bp.e_lo + r0_ - bp.w1;
            int r1_ = srow + 32, s1 = (r1_ < bp.w1) ? bp.prow1 + r1_ : bp.e_lo + r1_ - bp.w1;
            int r2_ = srow + 64, s2 = (r2_ < bp.w1) ? bp.prow1 + r2_ : bp.e_lo + r2_ - bp.w1;
            int r3_ = srow + 96, s3 = (r3_ < bp.w1) ? bp.prow1 + r3_ : bp.e_lo + r3_ - bp.w1;
            if (s0 > Tt - 1) s0 = Tt - 1;
            if (s1 > Tt - 1) s1 = Tt - 1;
            if (s2 > Tt - 1) s2 = Tt - 1;
            if (s3 > Tt - 1) s3 = Tt - 1;
            pr0 = *(const f32x4*)(p_g + (size_t)s0 * Dd + sseg * 8);
            pr1 = *(const f32x4*)(p_g + (size_t)s1 * Dd + sseg * 8);
            pr2 = *(const f32x4*)(p_g + (size_t)s2 * Dd + sseg * 8);
            pr3 = *(const f32x4*)(p_g + (size_t)s3 * Dd + sseg * 8);
        }

        // content scores
        f32x4 accS[4];
#pragma unroll
        for (int nt = 0; nt < 4; nt++) {
            f32x4 acc = {0.f, 0.f, 0.f, 0.f};
#pragma unroll
            for (int kc = 0; kc < 2; kc++) {
                bf16x8 bk8 = *(const bf16x8*)&k_s[nt * 16 + l16][kc * 32 + quad * 8];
                acc = __builtin_amdgcn_mfma_f32_16x16x32_bf16(aq[kc], bk8, acc, 0, 0, 0);
            }
            accS[nt] = acc;
        }

        // banded pos matmul -> strip-local skewed store (wave-private)
        for (int ct = 0; ct < bc.nct1 + bc.nct2; ct++) {
            bool b2 = ct >= bc.nct1;
            int rb_ = b2 ? (bc.w1 + (ct - bc.nct1) * 16) : (ct * 16);
            int cb_ = b2 ? (bc.c2_0 + (ct - bc.nct1) * 16) : (ct * 16);
            if (cb_ > cmax || cb_ + 15 < cmin) continue;
            f32x4 acc = {0.f, 0.f, 0.f, 0.f};
#pragma unroll
            for (int kc = 0; kc < 2; kc++) {
                bf16x8 bp8 = *(const bf16x8*)&pA[rb_ + l16][kc * 32 + quad * 8];
                acc = b2 ? __builtin_amdgcn_mfma_f32_16x16x32_bf16(av2[kc], bp8, acc, 0, 0, 0)
                         : __builtin_amdgcn_mfma_f32_16x16x32_bf16(av1[kc], bp8, acc, 0, 0, 0);
            }
            int colp = cb_ + l16 - off_w;          // strip-local
            if ((unsigned)colp < 80u) {
#pragma unroll
                for (int r = 0; r < 4; r++)
                    msw[wave * 16 + quad * 4 + r][colp] = (bf16_t)acc[r];
            }
        }
        // zero column for dd == -1 (strip-local)
        {
            int zcl = bc.d_hi + 1 - off_w;
            if ((unsigned)zcl < 80u && quad == 0)
                msw[wave * 16 + l16][zcl] = (bf16_t)0.f;
        }

        // gather all 16 (no aliasing stores in between), then write weights
        float wv[4][4];
#pragma unroll
        for (int nt = 0; nt < 4; nt++) {
#pragma unroll
            for (int r = 0; r < 4; r++) {
                float pos = (float)msw[wave * 16 + quad * 4 + r]
                                    [nt * 16 + l16 + 15 - (quad * 4 + r)];
                float x = accS[nt][r] + pos;
                float a = fminf(fmaf(x, 0.18033688f, -17.3123405f), 120.0f);
                float w = exp2f(a);
                lsum[r] += w;
                wv[nt][r] = w;
            }
        }
#pragma unroll
        for (int nt = 0; nt < 4; nt++)
#pragma unroll
            for (int r = 0; r < 4; r++)
                msw[wave * 16 + quad * 4 + r][nt * 16 + l16] = (bf16_t)wv[nt][r];

        // O += W @ V : A from own msw strip, B direct from VT ([d][t])
#pragma unroll
        for (int kc = 0; kc < 2; kc++) {
            bf16x8 aw = *(const bf16x8*)&msw[wave * 16 + l16][kc * 32 + quad * 8];
#pragma unroll
            for (int dt = 0; dt < 4; dt++) {
                bf16x8 bv8 = *(const bf16x8*)(vt_g + (size_t)(dt * 16 + l16) * Tt + j0 + kc * 32 + quad * 8);
                accO[dt] = __builtin_amdgcn_mfma_f32_16x16x32_bf16(aw, bv8, accO[dt], 0, 0, 0);
            }
        }
        __syncthreads();  // protect k_s/pA before next write phase
    }

#pragma unroll
    for (int r = 0; r < 4; r++) {
#pragma unroll
        for (int off = 1; off < 16; off <<= 1) lsum[r] += __shfl_xor(lsum[r], off, 64);
    }

#pragma unroll
    for (int r = 0; r < 4; r++) {
        int il = wave * 16 + quad * 4 + r;
        int ig = i0 + il;
        float inv = 1.0f / lsum[r];
#pragma unroll
        for (int dt = 0; dt < 4; dt++) {
            CTX[((size_t)(b * Tt + ig)) * Cc + h * Dd + dt * 16 + l16] = accO[dt][r] * inv;
        }
    }
}

// ---------------------------------------------------------------------------
extern "C" void kernel_launch(void* const* d_in, const int* in_sizes, int n_in,
                              void* d_out, int out_size, void* d_ws, size_t ws_size,
                              hipStream_t stream)
{
    const float* query = (const float*)d_in[0];
    const float* key   = (const float*)d_in[1];
    const float* value = (const float*)d_in[2];
    const float* pemb  = (const float*)d_in[3];
    const float* Wq    = (const float*)d_in[4];
    const float* bq    = (const float*)d_in[5];
    const float* Wk    = (const float*)d_in[6];
    const float* bk    = (const float*)d_in[7];
    const float* Wv    = (const float*)d_in[8];
    const float* bv    = (const float*)d_in[9];
    const float* Wpos  = (const float*)d_in[10];
    const float* pbu   = (const float*)d_in[11];
    const float* pbv   = (const float*)d_in[12];
    const float* Wo    = (const float*)d_in[13];
    const float* bo    = (const float*)d_in[14];

    const size_t NE = (size_t)Bb * Hh * Tt * Dd;  // 4,194,304 per tensor
    bf16_t* QU   = (bf16_t*)d_ws;
    bf16_t* QV   = QU + NE;
    bf16_t* K16  = QV + NE;
    bf16_t* VT16 = K16 + NE;
    bf16_t* P16  = VT16 + NE;
    float*  CTX  = (float*)(P16 + NE);            // ws >= 56 MB (unchanged)

    // W^T hi/lo planes overlaid on dead regions (no extra workspace):
    //  - WT4 (Wq,Wk,Wv,Wpos; 4 MB) in CTX region: dead until attn writes CTX.
    //  - WoT (1 MB) in QU region: written AFTER attn (QU dead by then).
    bf16_t* WT4 = (bf16_t*)CTX;
    bf16_t* WoT = (bf16_t*)QU;

    // prepass A: Wq/Wk/Wv/Wpos -> transposed hi/lo bf16 planes
    wsplit_kernel<<<dim3(64, 4), 256, 0, stream>>>(Wq, Wk, Wv, Wpos, Wo, WT4, WoT, -1);

    // QKVP projections (z = blockIdx.z)
    split_gemm_kernel<<<dim3(256, 1, 4), 256, 0, stream>>>(
        query, key, value, pemb, WT4,
        bq, bk, bv, pbu, pbv, QU, QV, K16, VT16, P16);

    attn_kernel<<<dim3(32, 32), 256, 0, stream>>>(QU, QV, K16, VT16, P16, CTX);

    // prepass B: Wo -> WoT (QU region now dead)
    wsplit_kernel<<<dim3(64, 1), 256, 0, stream>>>(Wq, Wk, Wv, Wpos, Wo, WT4, WoT, 4);

    // output projection: 64x128 tiles, 512 blocks, BK=32
    out_gemm_kernel<<<dim3(512), 256, 0, stream>>>(CTX, WoT, bo, (float*)d_out);
}